// Round 6
// baseline (129.060 us; speedup 1.0000x reference)
//
#include <hip/hip_runtime.h>
#include <math.h>

#define NTOK 96
#define EMBED 128
#define HEADS 4
#define HD 32
#define NROW (NTOK*NTOK)     // 9216
#define YT 16
#define NYT (NTOK/YT)        // 6

// ---------------- K1: pT[(y*96+x)] = row(x,y) of x@W+b ; murT stats ----------------
// 2304 blocks x 128 threads, 4 rows per block
__global__ __launch_bounds__(128) void k_proj(
    const float* __restrict__ x, const float* __restrict__ W,
    const float* __restrict__ b,
    float* __restrict__ pT, float* __restrict__ murT) {
  const int r0 = blockIdx.x * 4;         // global row = X*96 + y
  const int X  = r0 / NTOK;
  const int y0 = r0 % NTOK;
  const int e  = threadIdx.x;            // 0..127
  __shared__ float xt[EMBED][4];
  #pragma unroll
  for (int k = 0; k < 4; ++k)
    xt[e][k] = x[(size_t)(r0 + k) * EMBED + e];
  __syncthreads();

  const float bias = b[e];
  float a0 = bias, a1 = bias, a2 = bias, a3 = bias;
  #pragma unroll 8
  for (int i = 0; i < EMBED; ++i) {
    const float wv = W[(size_t)i * EMBED + e];
    const float4 c = *(const float4*)&xt[i][0];
    a0 = fmaf(wv, c.x, a0); a1 = fmaf(wv, c.y, a1);
    a2 = fmaf(wv, c.z, a2); a3 = fmaf(wv, c.w, a3);
  }

  const int h = e >> 5;
  float accs[4] = {a0, a1, a2, a3};
  #pragma unroll
  for (int k = 0; k < 4; ++k) {
    pT[((size_t)(y0 + k) * NTOK + X) * EMBED + e] = accs[k];
    float s1 = accs[k], s2 = accs[k] * accs[k];
    #pragma unroll
    for (int m_ = 1; m_ < 32; m_ <<= 1) {
      s1 += __shfl_xor(s1, m_, 64);
      s2 += __shfl_xor(s2, m_, 64);
    }
    if ((e & 31) == 0) {
      const float mu = s1 * (1.f / HD);
      const float var = fmaxf(s2 * (1.f / HD) - mu * mu, 0.f);
      float2 v; v.x = mu; v.y = rsqrtf(var + 1e-5f);
      *(float2*)&murT[(((size_t)(y0 + k) * NTOK + X) * HEADS + h) * 2] = v;
    }
  }
}

__device__ __forceinline__ void sc_elem(float e, float f, float g, float b,
    float rE, float pE, float rF, float pF,
    float& s, float& m, float& q, float& t) {
  const float uE = fmaf(e, rE, -pE);
  const float en = fmaf(uE, g, b);
  const float uF = fmaf(f, rF, -pF);
  const float fn = fmaf(uF, g, b);
  s = fmaf(en, fn, s);
  t = e * f;
  m += t;
  q = fmaf(t, t, q);
}

#define SC_QUAD(E4, F4, G4, B4, T4) \
  sc_elem(E4.x, F4.x, G4.x, B4.x, rE, pE, rF, pF, s, m, q, T4.x); \
  sc_elem(E4.y, F4.y, G4.y, B4.y, rE, pE, rF, pF, s, m, q, T4.y); \
  sc_elem(E4.z, F4.z, G4.z, B4.z, rE, pE, rF, pF, s, m, q, T4.z); \
  sc_elem(E4.w, F4.w, G4.w, B4.w, rE, pE, rF, pF, s, m, q, T4.w);

#define AGG_QUAD(A4, T4) \
  A4.x = fmaf(w, T4.x, A4.x); A4.y = fmaf(w, T4.y, A4.y); \
  A4.z = fmaf(w, T4.z, A4.z); A4.w = fmaf(w, T4.w, A4.w);

#define SCALE_QUAD(A4) \
  A4.x *= scale; A4.y *= scale; A4.z *= scale; A4.w *= scale;

#define RED_QUAD(A4, MASK) \
  A4.x += __shfl_xor(A4.x, MASK, 64); A4.y += __shfl_xor(A4.y, MASK, 64); \
  A4.z += __shfl_xor(A4.z, MASK, 64); A4.w += __shfl_xor(A4.w, MASK, 64);

// ---------------- K2: fused attention + product-LN agg + final GEMM + LN ----------------
// 576 blocks (yt-major: X = bid%96) x 512 threads = (hh:2, y:16, ds:2, da:8);
// two head-pairs looped (hl), 2 heads in flight per iteration.
__global__ __launch_bounds__(512) void k_fused(
    const float* __restrict__ pT, const float* __restrict__ murT,
    const float* __restrict__ ln_g, const float* __restrict__ ln_b,
    const float* __restrict__ x, const float* __restrict__ Wf,
    const float* __restrict__ bf, const float* __restrict__ g2,
    const float* __restrict__ b2, float* __restrict__ out) {
  const int bid = blockIdx.x;
  const int X   = bid % NTOK;          // yt-major: consecutive blocks share yt
  const int y0  = (bid / NTOK) * YT;

  const int tid = threadIdx.x;
  const int hh  = tid >> 8;            // head-in-pair
  const int y   = (tid >> 4) & 15;
  const int ds  = (tid >> 3) & 1;      // d-half
  const int da  = tid & 7;             // a-slice
  const int yy  = y0 + y;
  const int eoff = ds * 16;

  __shared__ float e_sm[2][NTOK][36];   // 27.6 KB
  __shared__ float mur_sm[2][NTOK][2];
  __shared__ float xt_sm[EMBED][20];    // x rows transposed [c][y]
  __shared__ float agg_t[EMBED][20];    // agg transposed [d][y]
  __shared__ float g_sm[HD], b_sm[HD];
  __shared__ float red_sm[8][4][2];

  // stage x rows (transposed): coalesced in col
  #pragma unroll
  for (int i = 0; i < 4; ++i) {
    const int g = tid + i * 512;       // 0..2047
    const int yl = g >> 7, col = g & 127;
    xt_sm[col][yl] = x[((size_t)(X * NTOK + y0 + yl)) * EMBED + col];
  }
  if (tid < HD) { g_sm[tid] = ln_g[tid]; b_sm[tid] = ln_b[tid]; }

  for (int hl = 0; hl < 2; ++hl) {
    __syncthreads();   // protect e_sm/mur_sm from previous iteration's readers
    #pragma unroll
    for (int i = 0; i < 3; ++i) {
      const int g = tid + i * 512;     // 0..1535
      const int h2 = g >> 9? (g >= 768 ? 1 : 1) : (g >= 768 ? 1 : 0);  // see below
      const int hd2 = (g >= 768) ? 1 : 0;
      const int rem = g - hd2 * 768;
      const int a = rem >> 3, qq = rem & 7;
      (void)h2;
      *(float4*)&e_sm[hd2][a][qq * 4] =
          *(const float4*)&pT[((size_t)a * NTOK + X) * EMBED + (hl * 2 + hd2) * HD + qq * 4];
    }
    if (tid < 192) {
      const int a = tid >> 1, h2s = tid & 1;
      *(float2*)&mur_sm[h2s][a][0] =
          *(const float2*)&murT[(((size_t)a * NTOK + X) * HEADS + hl * 2 + h2s) * 2];
    }
    __syncthreads();

    const int H = hl * 2 + hh;
    const float4 g0 = *(const float4*)&g_sm[eoff];
    const float4 g1 = *(const float4*)&g_sm[eoff + 4];
    const float4 g2v = *(const float4*)&g_sm[eoff + 8];
    const float4 g3 = *(const float4*)&g_sm[eoff + 12];
    const float4 b0 = *(const float4*)&b_sm[eoff];
    const float4 b1 = *(const float4*)&b_sm[eoff + 4];
    const float4 b2v = *(const float4*)&b_sm[eoff + 8];
    const float4 b3 = *(const float4*)&b_sm[eoff + 12];

    const float* fbase = pT + (size_t)yy * NTOK * EMBED + H * HD + eoff;
    const float* mbase = murT + ((size_t)yy * NTOK * HEADS + H) * 2;

    float4 acc0 = {0,0,0,0}, acc1 = {0,0,0,0}, acc2 = {0,0,0,0}, acc3 = {0,0,0,0};
    float den = 0.f, cc = 0.f, mx = -1e30f;

    #pragma unroll 2
    for (int ia = 0; ia < 12; ++ia) {
      const int a = ia * 8 + da;
      const float4* fp = (const float4*)(fbase + (size_t)a * EMBED);
      const float4 f0 = fp[0], f1 = fp[1], f2 = fp[2], f3 = fp[3];
      const float2 mrF = *(const float2*)(mbase + (size_t)a * (HEADS * 2));
      const float muE = mur_sm[hh][a][0], rE = mur_sm[hh][a][1];
      const float rF = mrF.y;
      const float pE = muE * rE;
      const float pF = mrF.x * rF;
      const float4 e0 = *(const float4*)&e_sm[hh][a][eoff];
      const float4 e1 = *(const float4*)&e_sm[hh][a][eoff + 4];
      const float4 e2 = *(const float4*)&e_sm[hh][a][eoff + 8];
      const float4 e3 = *(const float4*)&e_sm[hh][a][eoff + 12];

      float s = 0.f, m = 0.f, q = 0.f;
      float4 t0, t1, t2, t3;
      SC_QUAD(e0, f0, g0, b0, t0);
      SC_QUAD(e1, f1, g1, b1, t1);
      SC_QUAD(e2, f2, g2v, b2v, t2);
      SC_QUAD(e3, f3, g3, b3, t3);

      // combine d-halves (xor ds bit)
      s += __shfl_xor(s, 8, 64);
      m += __shfl_xor(m, 8, 64);
      q += __shfl_xor(q, 8, 64);

      const float mu = m * (1.f / HD);
      const float var = fmaxf(fmaf(-mu, mu, q * (1.f / HD)), 0.f);
      const float r = rsqrtf(var + 1e-5f);
      const float sc = s * 0.17677669529663687f;  // 1/sqrt(32)

      // online max over the 8 a's of this iteration (uniform in 16-lane group)
      float mc = sc;
      mc = fmaxf(mc, __shfl_xor(mc, 1, 64));
      mc = fmaxf(mc, __shfl_xor(mc, 2, 64));
      mc = fmaxf(mc, __shfl_xor(mc, 4, 64));
      const float nmx = fmaxf(mx, mc);
      const float scale = __expf(mx - nmx);
      mx = nmx;
      const float ex = __expf(sc - mx);
      const float w = ex * r;
      den = fmaf(den, scale, ex);
      cc  = fmaf(cc,  scale, w * mu);
      SCALE_QUAD(acc0); SCALE_QUAD(acc1); SCALE_QUAD(acc2); SCALE_QUAD(acc3);
      AGG_QUAD(acc0, t0);
      AGG_QUAD(acc1, t1);
      AGG_QUAD(acc2, t2);
      AGG_QUAD(acc3, t3);
    }

    // cross-a reduction over the 8 da lanes
    #pragma unroll
    for (int mask = 1; mask <= 4; mask <<= 1) {
      den += __shfl_xor(den, mask, 64);
      cc  += __shfl_xor(cc,  mask, 64);
      RED_QUAD(acc0, mask);
      RED_QUAD(acc1, mask);
      RED_QUAD(acc2, mask);
      RED_QUAD(acc3, mask);
    }

    if (da == 0) {
      const float inv = 1.f / den;
      float ov[16];
      ov[0]  = fmaf(g0.x, (acc0.x - cc) * inv, b0.x);
      ov[1]  = fmaf(g0.y, (acc0.y - cc) * inv, b0.y);
      ov[2]  = fmaf(g0.z, (acc0.z - cc) * inv, b0.z);
      ov[3]  = fmaf(g0.w, (acc0.w - cc) * inv, b0.w);
      ov[4]  = fmaf(g1.x, (acc1.x - cc) * inv, b1.x);
      ov[5]  = fmaf(g1.y, (acc1.y - cc) * inv, b1.y);
      ov[6]  = fmaf(g1.z, (acc1.z - cc) * inv, b1.z);
      ov[7]  = fmaf(g1.w, (acc1.w - cc) * inv, b1.w);
      ov[8]  = fmaf(g2v.x, (acc2.x - cc) * inv, b2v.x);
      ov[9]  = fmaf(g2v.y, (acc2.y - cc) * inv, b2v.y);
      ov[10] = fmaf(g2v.z, (acc2.z - cc) * inv, b2v.z);
      ov[11] = fmaf(g2v.w, (acc2.w - cc) * inv, b2v.w);
      ov[12] = fmaf(g3.x, (acc3.x - cc) * inv, b3.x);
      ov[13] = fmaf(g3.y, (acc3.y - cc) * inv, b3.y);
      ov[14] = fmaf(g3.z, (acc3.z - cc) * inv, b3.z);
      ov[15] = fmaf(g3.w, (acc3.w - cc) * inv, b3.w);
      #pragma unroll
      for (int j = 0; j < 16; ++j)
        agg_t[H * HD + eoff + j][y] = ov[j];
    }
  }
  __syncthreads();   // agg_t complete

  // ---- final: out = LN([x, agg] @ Wf + bf) over the block's 16 rows ----
  // 512 threads = (rh:4) x (e:128); 4 rows per thread-group
  const int e  = tid & 127;
  const int rh = tid >> 7;            // rows rh*4 .. rh*4+3
  const float bias = bf[e];
  float acc4[4] = {bias, bias, bias, bias};

  #pragma unroll 8
  for (int i = 0; i < EMBED; ++i) {
    const float wv = Wf[(size_t)i * EMBED + e];
    const float4 c0 = *(const float4*)&xt_sm[i][rh * 4];
    acc4[0] = fmaf(wv, c0.x, acc4[0]); acc4[1] = fmaf(wv, c0.y, acc4[1]);
    acc4[2] = fmaf(wv, c0.z, acc4[2]); acc4[3] = fmaf(wv, c0.w, acc4[3]);
  }
  #pragma unroll 8
  for (int i = 0; i < EMBED; ++i) {
    const float wv = Wf[(size_t)(EMBED + i) * EMBED + e];
    const float4 c0 = *(const float4*)&agg_t[i][rh * 4];
    acc4[0] = fmaf(wv, c0.x, acc4[0]); acc4[1] = fmaf(wv, c0.y, acc4[1]);
    acc4[2] = fmaf(wv, c0.z, acc4[2]); acc4[3] = fmaf(wv, c0.w, acc4[3]);
  }

  const int wid = tid >> 6;
  #pragma unroll
  for (int k = 0; k < 4; ++k) {
    float s1 = acc4[k], s2 = acc4[k] * acc4[k];
    #pragma unroll
    for (int m_ = 1; m_ < 64; m_ <<= 1) {
      s1 += __shfl_xor(s1, m_, 64);
      s2 += __shfl_xor(s2, m_, 64);
    }
    if ((tid & 63) == 0) { red_sm[wid][k][0] = s1; red_sm[wid][k][1] = s2; }
  }
  __syncthreads();

  const float gg = g2[e], bb = b2[e];
  #pragma unroll
  for (int k = 0; k < 4; ++k) {
    const float S1 = red_sm[wid][k][0] + red_sm[wid ^ 1][k][0];
    const float S2 = red_sm[wid][k][1] + red_sm[wid ^ 1][k][1];
    const float mu = S1 * (1.f / EMBED);
    const float var = fmaxf(S2 * (1.f / EMBED) - mu * mu, 0.f);
    const float rstd = rsqrtf(var + 1e-5f);
    out[((size_t)(X * NTOK + y0 + rh * 4 + k)) * EMBED + e] =
        (acc4[k] - mu) * rstd * gg + bb;
  }
}

extern "C" void kernel_launch(void* const* d_in, const int* in_sizes, int n_in,
                              void* d_out, int out_size, void* d_ws, size_t ws_size,
                              hipStream_t stream) {
  const float* x    = (const float*)d_in[0];
  const float* W    = (const float*)d_in[1];
  const float* b    = (const float*)d_in[2];
  const float* ln_g = (const float*)d_in[3];
  const float* ln_b = (const float*)d_in[4];
  const float* Wf   = (const float*)d_in[5];
  const float* bf   = (const float*)d_in[6];
  const float* g2   = (const float*)d_in[7];
  const float* b2   = (const float*)d_in[8];
  float* out = (float*)d_out;

  float* pT   = (float*)d_ws;                         // NROW*128
  float* murT = pT + (size_t)NROW * EMBED;            // NROW*4*2

  k_proj<<<NROW / 4, 128, 0, stream>>>(x, W, b, pT, murT);
  k_fused<<<NTOK * NYT, 512, 0, stream>>>(pT, murT, ln_g, ln_b,
                                          x, Wf, bf, g2, b2, out);
}

// Round 7
// 108.400 us; speedup vs baseline: 1.1906x; 1.1906x over previous
//
#include <hip/hip_runtime.h>
#include <math.h>

#define NTOK 96
#define EMBED 128
#define HEADS 4
#define HD 32
#define NROW (NTOK*NTOK)     // 9216
#define YT 8
#define NYT (NTOK/YT)        // 12

// ---------------- K1: pT[(y*96+x)] = row(x,y) of x@W+b ; murT stats ----------------
// 2304 blocks x 128 threads, 4 rows per block
__global__ __launch_bounds__(128) void k_proj(
    const float* __restrict__ x, const float* __restrict__ W,
    const float* __restrict__ b,
    float* __restrict__ pT, float* __restrict__ murT) {
  const int r0 = blockIdx.x * 4;         // global row = X*96 + y
  const int X  = r0 / NTOK;
  const int y0 = r0 % NTOK;
  const int e  = threadIdx.x;            // 0..127
  __shared__ float xt[EMBED][4];
  #pragma unroll
  for (int k = 0; k < 4; ++k)
    xt[e][k] = x[(size_t)(r0 + k) * EMBED + e];
  __syncthreads();

  const float bias = b[e];
  float a0 = bias, a1 = bias, a2 = bias, a3 = bias;
  #pragma unroll 8
  for (int i = 0; i < EMBED; ++i) {
    const float wv = W[(size_t)i * EMBED + e];
    const float4 c = *(const float4*)&xt[i][0];
    a0 = fmaf(wv, c.x, a0); a1 = fmaf(wv, c.y, a1);
    a2 = fmaf(wv, c.z, a2); a3 = fmaf(wv, c.w, a3);
  }

  const int h = e >> 5;
  float accs[4] = {a0, a1, a2, a3};
  #pragma unroll
  for (int k = 0; k < 4; ++k) {
    pT[((size_t)(y0 + k) * NTOK + X) * EMBED + e] = accs[k];
    float s1 = accs[k], s2 = accs[k] * accs[k];
    #pragma unroll
    for (int m_ = 1; m_ < 32; m_ <<= 1) {
      s1 += __shfl_xor(s1, m_, 64);
      s2 += __shfl_xor(s2, m_, 64);
    }
    if ((e & 31) == 0) {
      const float mu = s1 * (1.f / HD);
      const float var = fmaxf(s2 * (1.f / HD) - mu * mu, 0.f);
      float2 v; v.x = mu; v.y = rsqrtf(var + 1e-5f);
      *(float2*)&murT[(((size_t)(y0 + k) * NTOK + X) * HEADS + h) * 2] = v;
    }
  }
}

__device__ __forceinline__ void sc_elem(float e, float f, float g, float b,
    float rE, float pE, float rF, float pF,
    float& s, float& m, float& q, float& t) {
  const float uE = fmaf(e, rE, -pE);
  const float en = fmaf(uE, g, b);
  const float uF = fmaf(f, rF, -pF);
  const float fn = fmaf(uF, g, b);
  s = fmaf(en, fn, s);
  t = e * f;
  m += t;
  q = fmaf(t, t, q);
}

#define SC_QUAD(E4, F4, G4, B4, T4) \
  sc_elem(E4.x, F4.x, G4.x, B4.x, rE, pE, rF, pF, s, m, q, T4.x); \
  sc_elem(E4.y, F4.y, G4.y, B4.y, rE, pE, rF, pF, s, m, q, T4.y); \
  sc_elem(E4.z, F4.z, G4.z, B4.z, rE, pE, rF, pF, s, m, q, T4.z); \
  sc_elem(E4.w, F4.w, G4.w, B4.w, rE, pE, rF, pF, s, m, q, T4.w);

#define AGG_QUAD(A4, T4) \
  A4.x = fmaf(w, T4.x, A4.x); A4.y = fmaf(w, T4.y, A4.y); \
  A4.z = fmaf(w, T4.z, A4.z); A4.w = fmaf(w, T4.w, A4.w);

#define SCALE_QUAD(A4) \
  A4.x *= scale; A4.y *= scale; A4.z *= scale; A4.w *= scale;

#define RED_QUAD(A4, MASK) \
  A4.x += __shfl_xor(A4.x, MASK, 64); A4.y += __shfl_xor(A4.y, MASK, 64); \
  A4.z += __shfl_xor(A4.z, MASK, 64); A4.w += __shfl_xor(A4.w, MASK, 64);

// ---------------- K2: fused attention + product-LN agg + final GEMM + LN ----------------
// 1152 blocks (yt-major: X = bid%96, 8-row y-tiles) x 256 threads
// = (y:8, ds:2, da:16); 4 heads looped.
__global__ __launch_bounds__(256) void k_fused(
    const float* __restrict__ pT, const float* __restrict__ murT,
    const float* __restrict__ ln_g, const float* __restrict__ ln_b,
    const float* __restrict__ x, const float* __restrict__ Wf,
    const float* __restrict__ bf, const float* __restrict__ g2,
    const float* __restrict__ b2, float* __restrict__ out) {
  const int bid = blockIdx.x;
  const int X   = bid % NTOK;          // yt-major: consecutive blocks share yt
  const int y0  = (bid / NTOK) * YT;

  const int tid = threadIdx.x;
  const int y   = tid >> 5;            // 0..7
  const int ds  = (tid >> 4) & 1;      // d-half
  const int da  = tid & 15;            // a-slice (16 lanes)
  const int yy  = y0 + y;
  const int eoff = ds * 16;

  __shared__ float e_sm[NTOK][36];     // per-head e slice, 13.8 KB
  __shared__ float mur_sm[NTOK][2];
  __shared__ float xt_sm[EMBED][12];   // x rows transposed [c][y], 8+4 pad
  __shared__ float agg_t[EMBED][12];   // agg transposed [d][y]
  __shared__ float g_sm[HD], b_sm[HD];
  __shared__ float red_sm[4][4][2];

  // stage x rows (transposed): coalesced in col
  #pragma unroll
  for (int i = 0; i < 4; ++i) {
    const int g = tid + i * 256;       // 0..1023
    const int yl = g >> 7, col = g & 127;
    xt_sm[col][yl] = x[((size_t)(X * NTOK + y0 + yl)) * EMBED + col];
  }
  if (tid < HD) { g_sm[tid] = ln_g[tid]; b_sm[tid] = ln_b[tid]; }

  for (int H = 0; H < HEADS; ++H) {
    __syncthreads();   // protect e_sm/mur_sm from previous head's readers
    #pragma unroll
    for (int i = 0; i < 3; ++i) {
      const int g = tid + i * 256;     // 0..767
      const int a = g >> 3, qq = g & 7;
      *(float4*)&e_sm[a][qq * 4] =
          *(const float4*)&pT[((size_t)a * NTOK + X) * EMBED + H * HD + qq * 4];
    }
    if (tid < NTOK) {
      const float2 v = *(const float2*)&murT[(((size_t)tid * NTOK + X) * HEADS + H) * 2];
      mur_sm[tid][0] = v.x; mur_sm[tid][1] = v.y;
    }
    __syncthreads();

    const float4 g0 = *(const float4*)&g_sm[eoff];
    const float4 g1 = *(const float4*)&g_sm[eoff + 4];
    const float4 g2v = *(const float4*)&g_sm[eoff + 8];
    const float4 g3 = *(const float4*)&g_sm[eoff + 12];
    const float4 b0 = *(const float4*)&b_sm[eoff];
    const float4 b1 = *(const float4*)&b_sm[eoff + 4];
    const float4 b2v = *(const float4*)&b_sm[eoff + 8];
    const float4 b3 = *(const float4*)&b_sm[eoff + 12];

    const float* fbase = pT + (size_t)yy * NTOK * EMBED + H * HD + eoff;
    const float* mbase = murT + ((size_t)yy * NTOK * HEADS + H) * 2;

    float4 acc0 = {0,0,0,0}, acc1 = {0,0,0,0}, acc2 = {0,0,0,0}, acc3 = {0,0,0,0};
    float den = 0.f, cc = 0.f, mx = -1e30f;

    #pragma unroll 2
    for (int ia = 0; ia < 6; ++ia) {
      const int a = ia * 16 + da;
      const float4* fp = (const float4*)(fbase + (size_t)a * EMBED);
      const float4 f0 = fp[0], f1 = fp[1], f2 = fp[2], f3 = fp[3];
      const float2 mrF = *(const float2*)(mbase + (size_t)a * (HEADS * 2));
      const float muE = mur_sm[a][0], rE = mur_sm[a][1];
      const float rF = mrF.y;
      const float pE = muE * rE;
      const float pF = mrF.x * rF;
      const float4 e0 = *(const float4*)&e_sm[a][eoff];
      const float4 e1 = *(const float4*)&e_sm[a][eoff + 4];
      const float4 e2 = *(const float4*)&e_sm[a][eoff + 8];
      const float4 e3 = *(const float4*)&e_sm[a][eoff + 12];

      float s = 0.f, m = 0.f, q = 0.f;
      float4 t0, t1, t2, t3;
      SC_QUAD(e0, f0, g0, b0, t0);
      SC_QUAD(e1, f1, g1, b1, t1);
      SC_QUAD(e2, f2, g2v, b2v, t2);
      SC_QUAD(e3, f3, g3, b3, t3);

      // combine d-halves (xor ds bit)
      s += __shfl_xor(s, 16, 64);
      m += __shfl_xor(m, 16, 64);
      q += __shfl_xor(q, 16, 64);

      const float mu = m * (1.f / HD);
      const float var = fmaxf(fmaf(-mu, mu, q * (1.f / HD)), 0.f);
      const float r = rsqrtf(var + 1e-5f);
      const float sc = s * 0.17677669529663687f;  // 1/sqrt(32)

      // online max over the 16 a's of this iteration (uniform in 32-lane group)
      float mc = sc;
      mc = fmaxf(mc, __shfl_xor(mc, 1, 64));
      mc = fmaxf(mc, __shfl_xor(mc, 2, 64));
      mc = fmaxf(mc, __shfl_xor(mc, 4, 64));
      mc = fmaxf(mc, __shfl_xor(mc, 8, 64));
      const float nmx = fmaxf(mx, mc);
      const float scale = __expf(mx - nmx);
      mx = nmx;
      const float ex = __expf(sc - mx);
      const float w = ex * r;
      den = fmaf(den, scale, ex);
      cc  = fmaf(cc,  scale, w * mu);
      SCALE_QUAD(acc0); SCALE_QUAD(acc1); SCALE_QUAD(acc2); SCALE_QUAD(acc3);
      AGG_QUAD(acc0, t0);
      AGG_QUAD(acc1, t1);
      AGG_QUAD(acc2, t2);
      AGG_QUAD(acc3, t3);
    }

    // cross-a reduction over the 16 da lanes
    #pragma unroll
    for (int mask = 1; mask <= 8; mask <<= 1) {
      den += __shfl_xor(den, mask, 64);
      cc  += __shfl_xor(cc,  mask, 64);
      RED_QUAD(acc0, mask);
      RED_QUAD(acc1, mask);
      RED_QUAD(acc2, mask);
      RED_QUAD(acc3, mask);
    }

    if (da == 0) {
      const float inv = 1.f / den;
      float ov[16];
      ov[0]  = fmaf(g0.x, (acc0.x - cc) * inv, b0.x);
      ov[1]  = fmaf(g0.y, (acc0.y - cc) * inv, b0.y);
      ov[2]  = fmaf(g0.z, (acc0.z - cc) * inv, b0.z);
      ov[3]  = fmaf(g0.w, (acc0.w - cc) * inv, b0.w);
      ov[4]  = fmaf(g1.x, (acc1.x - cc) * inv, b1.x);
      ov[5]  = fmaf(g1.y, (acc1.y - cc) * inv, b1.y);
      ov[6]  = fmaf(g1.z, (acc1.z - cc) * inv, b1.z);
      ov[7]  = fmaf(g1.w, (acc1.w - cc) * inv, b1.w);
      ov[8]  = fmaf(g2v.x, (acc2.x - cc) * inv, b2v.x);
      ov[9]  = fmaf(g2v.y, (acc2.y - cc) * inv, b2v.y);
      ov[10] = fmaf(g2v.z, (acc2.z - cc) * inv, b2v.z);
      ov[11] = fmaf(g2v.w, (acc2.w - cc) * inv, b2v.w);
      ov[12] = fmaf(g3.x, (acc3.x - cc) * inv, b3.x);
      ov[13] = fmaf(g3.y, (acc3.y - cc) * inv, b3.y);
      ov[14] = fmaf(g3.z, (acc3.z - cc) * inv, b3.z);
      ov[15] = fmaf(g3.w, (acc3.w - cc) * inv, b3.w);
      #pragma unroll
      for (int j = 0; j < 16; ++j)
        agg_t[H * HD + eoff + j][y] = ov[j];
    }
  }
  __syncthreads();   // agg_t complete

  // ---- final: out = LN([x, agg] @ Wf + bf) over the block's 8 rows ----
  // 256 threads = (rh:2) x (e:128); 4 rows per thread
  const int e  = tid & 127;
  const int rh = tid >> 7;            // rows rh*4 .. rh*4+3
  const float bias = bf[e];
  float acc4[4] = {bias, bias, bias, bias};

  #pragma unroll 8
  for (int i = 0; i < EMBED; ++i) {
    const float wv = Wf[(size_t)i * EMBED + e];
    const float4 c0 = *(const float4*)&xt_sm[i][rh * 4];
    acc4[0] = fmaf(wv, c0.x, acc4[0]); acc4[1] = fmaf(wv, c0.y, acc4[1]);
    acc4[2] = fmaf(wv, c0.z, acc4[2]); acc4[3] = fmaf(wv, c0.w, acc4[3]);
  }
  #pragma unroll 8
  for (int i = 0; i < EMBED; ++i) {
    const float wv = Wf[(size_t)(EMBED + i) * EMBED + e];
    const float4 c0 = *(const float4*)&agg_t[i][rh * 4];
    acc4[0] = fmaf(wv, c0.x, acc4[0]); acc4[1] = fmaf(wv, c0.y, acc4[1]);
    acc4[2] = fmaf(wv, c0.z, acc4[2]); acc4[3] = fmaf(wv, c0.w, acc4[3]);
  }

  const int wid = tid >> 6;
  #pragma unroll
  for (int k = 0; k < 4; ++k) {
    float s1 = acc4[k], s2 = acc4[k] * acc4[k];
    #pragma unroll
    for (int m_ = 1; m_ < 64; m_ <<= 1) {
      s1 += __shfl_xor(s1, m_, 64);
      s2 += __shfl_xor(s2, m_, 64);
    }
    if ((tid & 63) == 0) { red_sm[wid][k][0] = s1; red_sm[wid][k][1] = s2; }
  }
  __syncthreads();

  const float gg = g2[e], bb = b2[e];
  #pragma unroll
  for (int k = 0; k < 4; ++k) {
    const float S1 = red_sm[wid][k][0] + red_sm[wid ^ 1][k][0];
    const float S2 = red_sm[wid][k][1] + red_sm[wid ^ 1][k][1];
    const float mu = S1 * (1.f / EMBED);
    const float var = fmaxf(S2 * (1.f / EMBED) - mu * mu, 0.f);
    const float rstd = rsqrtf(var + 1e-5f);
    out[((size_t)(X * NTOK + y0 + rh * 4 + k)) * EMBED + e] =
        (acc4[k] - mu) * rstd * gg + bb;
  }
}

extern "C" void kernel_launch(void* const* d_in, const int* in_sizes, int n_in,
                              void* d_out, int out_size, void* d_ws, size_t ws_size,
                              hipStream_t stream) {
  const float* x    = (const float*)d_in[0];
  const float* W    = (const float*)d_in[1];
  const float* b    = (const float*)d_in[2];
  const float* ln_g = (const float*)d_in[3];
  const float* ln_b = (const float*)d_in[4];
  const float* Wf   = (const float*)d_in[5];
  const float* bf   = (const float*)d_in[6];
  const float* g2   = (const float*)d_in[7];
  const float* b2   = (const float*)d_in[8];
  float* out = (float*)d_out;

  float* pT   = (float*)d_ws;                         // NROW*128
  float* murT = pT + (size_t)NROW * EMBED;            // NROW*4*2

  k_proj<<<NROW / 4, 128, 0, stream>>>(x, W, b, pT, murT);
  k_fused<<<NTOK * NYT, 256, 0, stream>>>(pT, murT, ln_g, ln_b,
                                          x, Wf, bf, g2, b2, out);
}